// Round 3
// baseline (30.985 us; speedup 1.0000x reference)
//
#include <hip/hip_runtime.h>
#include <math.h>

// Problem constants (match reference setup_inputs)
constexpr int B = 32;
constexpr int C = 1024;
constexpr int T = 1024;
constexpr int N = 3;
constexpr int CPB = 16;  // channels per block  -> grid = 32*64 = 2048 blocks
constexpr int CPW = 4;   // channels per wave   (CPB / 4 waves)

__device__ __forceinline__ float wred(float x) {
#pragma unroll
  for (int off = 32; off > 0; off >>= 1) x += __shfl_down(x, off);
  return x;
}

__device__ __forceinline__ float dot4(const float4 a, const float4 b) {
  return a.x * b.x + a.y * b.y + a.z * b.z + a.w * b.w;
}

// ---------------------------------------------------------------------------
// Single fused kernel, register-only (no LDS, no __syncthreads):
//   * each wave owns 4 channel rows of one batch
//   * lane L always consumes t-positions {4*(L+64k)+j} -> its 48 weight
//     values (3 filters x 16 positions) are computed once into VGPRs
//   * normalization is deferred: o = pref*dot_u / (pref*sum_u + 1e-6),
//     where u = 1/(1+d^2) -- so NO cross-lane work before pooling
//   * rows 0,1 are prefetched BEFORE the weight prologue (HBM latency
//     hides under the tanh/rcp math), rows 2,3 double-buffer behind FMAs
//   * one epilogue: 15 independent wave shuffle-reductions, lane 0 stores
// ---------------------------------------------------------------------------
__global__ __launch_bounds__(256) void tsf_fused(
    const float* __restrict__ v /* [B][C][T] */,
    const int* __restrict__ length,
    const float* __restrict__ center,
    const float* __restrict__ gamma_,
    float* __restrict__ out /* [B][C][N] */) {
  const int groups_per_b = C / CPB;
  const int b = blockIdx.x / groups_per_b;
  const int cg = blockIdx.x % groups_per_b;
  const int lane = threadIdx.x & 63;
  const int wv = threadIdx.x >> 6;
  const int ch0 = cg * CPB + wv * CPW;

  const float4* row0 = (const float4*)(v + ((size_t)b * C + ch0 + 0) * T);
  const float4* row1 = (const float4*)(v + ((size_t)b * C + ch0 + 1) * T);
  const float4* row2 = (const float4*)(v + ((size_t)b * C + ch0 + 2) * T);
  const float4* row3 = (const float4*)(v + ((size_t)b * C + ch0 + 3) * T);

  // ---- prefetch rows 0,1 (issued before the ALU prologue) ----
  float4 xa0 = row0[lane];
  float4 xa1 = row0[lane + 64];
  float4 xa2 = row0[lane + 128];
  float4 xa3 = row0[lane + 192];
  float4 xb0 = row1[lane];
  float4 xb1 = row1[lane + 64];
  float4 xb2 = row1[lane + 128];
  float4 xb3 = row1[lane + 192];

  // ---- per-lane unnormalized weights u = 1/(1+d^2) for own t-positions ----
  const float lf = (float)length[b];
  float4 w[N][4];
  float s[N];
  float pref[N];
#pragma unroll
  for (int n = 0; n < N; ++n) {
    const float c = tanhf(center[n]);
    const float g = tanhf(gamma_[n]);
    const float ctr = (lf - 1.0f) * (c + 1.0f) * 0.5f;
    const float gam = expf(1.5f - 2.0f * fabsf(g));
    const float a = 1.0f / gam;    // d = t*a + bb
    const float bb = -ctr * a;
    pref[n] = 1.0f / (3.14159265358979f * gam);
    s[n] = 0.0f;
#pragma unroll
    for (int k = 0; k < 4; ++k) {
      const float t0 = (float)(4 * lane + 256 * k);
      float4 wk;
      float d;
      d = fmaf(t0 + 0.0f, a, bb); wk.x = 1.0f / fmaf(d, d, 1.0f);
      d = fmaf(t0 + 1.0f, a, bb); wk.y = 1.0f / fmaf(d, d, 1.0f);
      d = fmaf(t0 + 2.0f, a, bb); wk.z = 1.0f / fmaf(d, d, 1.0f);
      d = fmaf(t0 + 3.0f, a, bb); wk.w = 1.0f / fmaf(d, d, 1.0f);
      w[n][k] = wk;
      s[n] += (wk.x + wk.y) + (wk.z + wk.w);
    }
  }

  float acc[CPW][N];

  // ---- channel 0 (buffer A), then refill A with row 2 ----
#pragma unroll
  for (int n = 0; n < N; ++n)
    acc[0][n] = dot4(xa0, w[n][0]) + dot4(xa1, w[n][1]) +
                dot4(xa2, w[n][2]) + dot4(xa3, w[n][3]);
  xa0 = row2[lane];
  xa1 = row2[lane + 64];
  xa2 = row2[lane + 128];
  xa3 = row2[lane + 192];

  // ---- channel 1 (buffer B), then refill B with row 3 ----
#pragma unroll
  for (int n = 0; n < N; ++n)
    acc[1][n] = dot4(xb0, w[n][0]) + dot4(xb1, w[n][1]) +
                dot4(xb2, w[n][2]) + dot4(xb3, w[n][3]);
  xb0 = row3[lane];
  xb1 = row3[lane + 64];
  xb2 = row3[lane + 128];
  xb3 = row3[lane + 192];

  // ---- channels 2, 3 ----
#pragma unroll
  for (int n = 0; n < N; ++n)
    acc[2][n] = dot4(xa0, w[n][0]) + dot4(xa1, w[n][1]) +
                dot4(xa2, w[n][2]) + dot4(xa3, w[n][3]);
#pragma unroll
  for (int n = 0; n < N; ++n)
    acc[3][n] = dot4(xb0, w[n][0]) + dot4(xb1, w[n][1]) +
                dot4(xb2, w[n][2]) + dot4(xb3, w[n][3]);

  // ---- epilogue: 15 independent wave reductions, then scaled stores ----
#pragma unroll
  for (int cc = 0; cc < CPW; ++cc)
#pragma unroll
    for (int n = 0; n < N; ++n) acc[cc][n] = wred(acc[cc][n]);
#pragma unroll
  for (int n = 0; n < N; ++n) s[n] = wred(s[n]);

  if (lane == 0) {
#pragma unroll
    for (int n = 0; n < N; ++n) {
      // o = pref*dot / (pref*sum + 1e-6)
      const float scale = pref[n] / fmaf(pref[n], s[n], 1e-6f);
#pragma unroll
      for (int cc = 0; cc < CPW; ++cc)
        out[((size_t)b * C + ch0 + cc) * N + n] = acc[cc][n] * scale;
    }
  }
}

// ---------------------------------------------------------------------------
extern "C" void kernel_launch(void* const* d_in, const int* in_sizes, int n_in,
                              void* d_out, int out_size, void* d_ws,
                              size_t ws_size, hipStream_t stream) {
  const float* video = (const float*)d_in[0];   // (B, C, T, 1, 1) fp32
  const int* length = (const int*)d_in[1];      // (B,) int32
  const float* center = (const float*)d_in[2];  // (N,) fp32
  // d_in[3] = delta (unused by reference)
  const float* gamma_ = (const float*)d_in[4];  // (N,) fp32
  float* out = (float*)d_out;                   // (B, C*N) fp32

  tsf_fused<<<B * (C / CPB), 256, 0, stream>>>(video, length, center, gamma_,
                                               out);
}